// Round 1
// baseline (82.712 us; speedup 1.0000x reference)
//
#include <hip/hip_runtime.h>
#include <math.h>

// Problem constants
#define B_   8
#define C1   256
#define HW1  4096   // 64*64
#define C2   512
#define HW2  1024   // 32*32
#define CK   64     // channel chunk per block

// ws float offsets
#define ACC   0                    // [0]=lat, [1]=slam1, [2]=slam2, [3]=pad
#define AS1S  4
#define AS1T  (AS1S + B_*HW1)
#define CS1S  (AS1T + B_*HW1)
#define CS1T  (CS1S + B_*C1)
#define AS2S  (CS1T + B_*C1)
#define AS2T  (AS2S + B_*HW2)
#define CS2S  (AS2T + B_*HW2)
#define CS2T  (CS2S + B_*C2)
#define ZEND  (CS2T + B_*C2)       // everything below here must be zeroed each call
#define MS1   ZEND
#define MC1   (MS1 + B_*HW1)
#define MS2   (MC1 + B_*C1)
#define MC2   (MS2 + B_*HW2)
#define WS_FLOATS (MC2 + B_*C2)

__device__ __forceinline__ float wave_reduce_sum(float v) {
#pragma unroll
    for (int off = 1; off < 64; off <<= 1) v += __shfl_xor(v, off, 64);
    return v;
}
__device__ __forceinline__ float wave_reduce_max(float v) {
#pragma unroll
    for (int off = 1; off < 64; off <<= 1) v = fmaxf(v, __shfl_xor(v, off, 64));
    return v;
}

__device__ __forceinline__ float block_reduce_sum(float v, float* red) {
    const int lane = threadIdx.x & 63, wid = threadIdx.x >> 6;
    v = wave_reduce_sum(v);
    if (lane == 0) red[wid] = v;
    __syncthreads();
    v = red[0] + red[1] + red[2] + red[3];
    __syncthreads();
    return v;
}
__device__ __forceinline__ float block_reduce_max(float v, float* red) {
    const int lane = threadIdx.x & 63, wid = threadIdx.x >> 6;
    v = wave_reduce_max(v);
    if (lane == 0) red[wid] = v;
    __syncthreads();
    v = fmaxf(fmaxf(red[0], red[1]), fmaxf(red[2], red[3]));
    __syncthreads();
    return v;
}

// ---------------- stats: As[b,hw] = sum_c |x|,  Cs[b,c] = sum_hw |x| ----------------
template<int C, int HW>
__device__ void stats_level(const float* __restrict__ s, const float* __restrict__ t,
                            float* As_s, float* As_t, float* Cs_s, float* Cs_t,
                            int b, int tile, int chunk, float* part /* 2*CK*4 floats */) {
    const int tid = threadIdx.x, lane = tid & 63, wid = tid >> 6;
    const int hw = tile * 256 + tid;
    const int c0 = chunk * CK;
    const size_t base = ((size_t)(b * C + c0)) * HW + hw;
    const float* ps = s + base;
    const float* pt = t + base;
    float gs = 0.f, gt = 0.f;
#pragma unroll 4
    for (int ci = 0; ci < CK; ++ci) {
        float vs = fabsf(ps[(size_t)ci * HW]);
        float vt = fabsf(pt[(size_t)ci * HW]);
        gs += vs; gt += vt;
        vs = wave_reduce_sum(vs);
        vt = wave_reduce_sum(vt);
        if (lane == 0) {
            part[(0 * CK + ci) * 4 + wid] = vs;
            part[(1 * CK + ci) * 4 + wid] = vt;
        }
    }
    atomicAdd(&As_s[b * HW + hw], gs);
    atomicAdd(&As_t[b * HW + hw], gt);
    __syncthreads();
    if (tid < 2 * CK) {
        float v = part[tid * 4] + part[tid * 4 + 1] + part[tid * 4 + 2] + part[tid * 4 + 3];
        const int ci = tid & (CK - 1);
        float* dst = (tid < CK) ? Cs_s : Cs_t;
        atomicAdd(&dst[b * C + c0 + ci], v);
    }
}

__global__ __launch_bounds__(256) void stats_kernel(const float* __restrict__ s1, const float* __restrict__ t1,
                                                    const float* __restrict__ s2, const float* __restrict__ t2,
                                                    float* ws) {
    __shared__ float part[2 * CK * 4];
    const int bid = blockIdx.x;
    if (bid < 512) {   // level 1: 8 b * 16 tiles * 4 chunks
        const int b = bid >> 6, rem = bid & 63, tile = rem >> 2, chunk = rem & 3;
        stats_level<C1, HW1>(s1, t1, ws + AS1S, ws + AS1T, ws + CS1S, ws + CS1T, b, tile, chunk, part);
    } else {           // level 2: 8 b * 4 tiles * 8 chunks
        const int bid2 = bid - 512;
        const int b = bid2 >> 5, rem = bid2 & 31, tile = rem >> 3, chunk = rem & 7;
        stats_level<C2, HW2>(s2, t2, ws + AS2S, ws + AS2T, ws + CS2S, ws + CS2T, b, tile, chunk, part);
    }
}

// ---------------- softmax + lat ----------------
__global__ __launch_bounds__(256) void softmax_kernel(float* ws) {
    __shared__ float red[4];
    const int bid = blockIdx.x;
    const int b = bid >> 2, m = bid & 3;
    const float* xa; const float* xb; float* M;
    int n; float scale, mult;
    if (m == 0)      { xa = ws + AS1S + b * HW1; xb = ws + AS1T + b * HW1; M = ws + MS1 + b * HW1; n = HW1; scale = 1.0f / C1;  mult = (float)HW1; }
    else if (m == 1) { xa = ws + CS1S + b * C1;  xb = ws + CS1T + b * C1;  M = ws + MC1 + b * C1;  n = C1;  scale = 1.0f / HW1; mult = (float)C1;  }
    else if (m == 2) { xa = ws + AS2S + b * HW2; xb = ws + AS2T + b * HW2; M = ws + MS2 + b * HW2; n = HW2; scale = 1.0f / C2;  mult = (float)HW2; }
    else             { xa = ws + CS2S + b * C2;  xb = ws + CS2T + b * C2;  M = ws + MC2 + b * C2;  n = C2;  scale = 1.0f / HW2; mult = (float)C2;  }

    const int tid = threadIdx.x;
    const float invT = 2.0f;  // 1/T, T=0.5
    float latp = 0.f, mx = -3.0e38f;
    for (int i = tid; i < n; i += 256) {
        float a = xa[i] * scale, c = xb[i] * scale;
        float d = a - c; latp += d * d;
        mx = fmaxf(mx, (a + c) * invT);
    }
    const float mxall = block_reduce_max(mx, red);
    const float latall = block_reduce_sum(latp, red);
    if (tid == 0) atomicAdd(&ws[ACC + 0], latall);

    float se = 0.f;
    for (int i = tid; i < n; i += 256) {
        float x = (xa[i] + xb[i]) * scale * invT;
        se += expf(x - mxall);
    }
    const float seall = block_reduce_sum(se, red);
    const float inv = mult / seall;
    for (int i = tid; i < n; i += 256) {
        float x = (xa[i] + xb[i]) * scale * invT;
        M[i] = expf(x - mxall) * inv;
    }
}

// ---------------- slam: sum Mc[b,c]*Ms[b,hw]*(s-t)^2 ----------------
template<int C, int HW>
__device__ void slam_level(const float* __restrict__ s, const float* __restrict__ t,
                           const float* Ms, const float* Mc, float* slam_acc,
                           int b, int tile, int chunk, float* mc, float* red) {
    const int tid = threadIdx.x;
    const int hw = tile * 256 + tid;
    const int c0 = chunk * CK;
    if (tid < CK) mc[tid] = Mc[b * C + c0 + tid];
    __syncthreads();
    const size_t base = ((size_t)(b * C + c0)) * HW + hw;
    const float* ps = s + base;
    const float* pt = t + base;
    float acc = 0.f;
#pragma unroll 8
    for (int ci = 0; ci < CK; ++ci) {
        float d = ps[(size_t)ci * HW] - pt[(size_t)ci * HW];
        acc += mc[ci] * d * d;
    }
    acc *= Ms[b * HW + hw];
    acc = block_reduce_sum(acc, red);
    if (tid == 0) atomicAdd(slam_acc, acc);
}

__global__ __launch_bounds__(256) void slam_kernel(const float* __restrict__ s1, const float* __restrict__ t1,
                                                   const float* __restrict__ s2, const float* __restrict__ t2,
                                                   float* ws) {
    __shared__ float mc[CK];
    __shared__ float red[4];
    const int bid = blockIdx.x;
    if (bid < 512) {
        const int b = bid >> 6, rem = bid & 63, tile = rem >> 2, chunk = rem & 3;
        slam_level<C1, HW1>(s1, t1, ws + MS1, ws + MC1, ws + ACC + 1, b, tile, chunk, mc, red);
    } else {
        const int bid2 = bid - 512;
        const int b = bid2 >> 5, rem = bid2 & 31, tile = rem >> 3, chunk = rem & 7;
        slam_level<C2, HW2>(s2, t2, ws + MS2, ws + MC2, ws + ACC + 2, b, tile, chunk, mc, red);
    }
}

// ---------------- epilogue ----------------
__global__ void final_kernel(const float* __restrict__ ws, float* __restrict__ out) {
    if (threadIdx.x == 0 && blockIdx.x == 0) {
        const float lat = ws[ACC + 0];
        const float lam = sqrtf(ws[ACC + 1]) + sqrtf(ws[ACC + 2]);
        // att = ATT * (A_COEF*lat + B_COEF*lam) / BS / n_levels
        const float att = (4e-4f * lat + 2e-2f * lam) / 8.0f / 2.0f;
        out[0] = att * 8.0f;
        out[1] = att;
    }
}

extern "C" void kernel_launch(void* const* d_in, const int* in_sizes, int n_in,
                              void* d_out, int out_size, void* d_ws, size_t ws_size,
                              hipStream_t stream) {
    const float* s1 = (const float*)d_in[1];
    const float* t1 = (const float*)d_in[2];
    const float* s2 = (const float*)d_in[3];
    const float* t2 = (const float*)d_in[4];
    float* ws = (float*)d_ws;
    float* out = (float*)d_out;

    // zero the atomic-accumulated region (harness does not re-poison between replays)
    hipMemsetAsync(ws, 0, (size_t)ZEND * sizeof(float), stream);

    stats_kernel<<<768, 256, 0, stream>>>(s1, t1, s2, t2, ws);
    softmax_kernel<<<32, 256, 0, stream>>>(ws);
    slam_kernel<<<768, 256, 0, stream>>>(s1, t1, s2, t2, ws);
    final_kernel<<<1, 64, 0, stream>>>(ws, out);
}

// Round 2
// 76.172 us; speedup vs baseline: 1.0858x; 1.0858x over previous
//
#include <hip/hip_runtime.h>
#include <math.h>

// Problem constants
#define B_   8
#define C1   256
#define HW1  4096   // 64*64
#define C2   512
#define HW2  1024   // 32*32

#define CCH  16     // channels per block
#define SUB  8      // channels per LDS-reduce subchunk
#define HWT  1024   // hw elements per block (256 threads * float4)

// ws float offsets
#define ACC   0                    // [0]=lat, [1]=slam1, [2]=slam2, [3]=pad
#define AS1S  4
#define AS1T  (AS1S + B_*HW1)
#define CS1S  (AS1T + B_*HW1)
#define CS1T  (CS1S + B_*C1)
#define AS2S  (CS1T + B_*C1)
#define AS2T  (AS2S + B_*HW2)
#define CS2S  (AS2T + B_*HW2)
#define CS2T  (CS2S + B_*C2)
#define ZEND  (CS2T + B_*C2)       // everything below here must be zeroed each call
#define MS1   ZEND
#define MC1   (MS1 + B_*HW1)
#define MS2   (MC1 + B_*C1)
#define MC2   (MS2 + B_*HW2)
#define WS_FLOATS (MC2 + B_*C2)

__device__ __forceinline__ float wave_reduce_sum(float v) {
#pragma unroll
    for (int off = 1; off < 64; off <<= 1) v += __shfl_xor(v, off, 64);
    return v;
}
__device__ __forceinline__ float wave_reduce_max(float v) {
#pragma unroll
    for (int off = 1; off < 64; off <<= 1) v = fmaxf(v, __shfl_xor(v, off, 64));
    return v;
}

__device__ __forceinline__ float block_reduce_sum(float v, float* red) {
    const int lane = threadIdx.x & 63, wid = threadIdx.x >> 6;
    v = wave_reduce_sum(v);
    if (lane == 0) red[wid] = v;
    __syncthreads();
    v = red[0] + red[1] + red[2] + red[3];
    __syncthreads();
    return v;
}
__device__ __forceinline__ float block_reduce_max(float v, float* red) {
    const int lane = threadIdx.x & 63, wid = threadIdx.x >> 6;
    v = wave_reduce_max(v);
    if (lane == 0) red[wid] = v;
    __syncthreads();
    v = fmaxf(fmaxf(red[0], red[1]), fmaxf(red[2], red[3]));
    __syncthreads();
    return v;
}

// ---------------- stats: As[b,hw] = sum_c |x|,  Cs[b,c] = sum_hw |x| ----------------
// Hot loop has NO cross-lane ops: float4 loads, register As accumulation,
// channel partials to LDS; LDS columns reduced in a separate phase.
template<int C, int HW>
__device__ void stats_level(const float* __restrict__ s, const float* __restrict__ t,
                            float* As_s, float* As_t, float* Cs_s, float* Cs_t,
                            int b, int tile, int chunk,
                            float (*part)[SUB][256] /* [2][SUB][256] */) {
    const int tid = threadIdx.x, lane = tid & 63, wid = tid >> 6;
    const int hw0 = tile * HWT + tid * 4;
    const int c0 = chunk * CCH;
    const size_t base = ((size_t)(b * C + c0)) * HW + hw0;
    const float4* ps = reinterpret_cast<const float4*>(s + base);
    const float4* pt = reinterpret_cast<const float4*>(t + base);
    const int cstride = HW / 4;   // float4 stride per channel

    float as_s[4] = {0.f, 0.f, 0.f, 0.f};
    float as_t[4] = {0.f, 0.f, 0.f, 0.f};

#pragma unroll
    for (int sub = 0; sub < CCH / SUB; ++sub) {
#pragma unroll
        for (int ci = 0; ci < SUB; ++ci) {
            const int cc = sub * SUB + ci;
            float4 vs = ps[(size_t)cc * cstride];
            float4 vt = pt[(size_t)cc * cstride];
            float a0 = fabsf(vs.x), a1 = fabsf(vs.y), a2 = fabsf(vs.z), a3 = fabsf(vs.w);
            float b0 = fabsf(vt.x), b1 = fabsf(vt.y), b2 = fabsf(vt.z), b3 = fabsf(vt.w);
            as_s[0] += a0; as_s[1] += a1; as_s[2] += a2; as_s[3] += a3;
            as_t[0] += b0; as_t[1] += b1; as_t[2] += b2; as_t[3] += b3;
            part[0][ci][tid] = (a0 + a1) + (a2 + a3);
            part[1][ci][tid] = (b0 + b1) + (b2 + b3);
        }
        __syncthreads();
        // reduce 16 columns (SUB channels x 2 tensors), 4 per wave
#pragma unroll
        for (int k = 0; k < 4; ++k) {
            const int col = (wid << 2) | k;      // 0..15
            const int tt = col >> 3, cc = col & 7;
            const float* cb = &part[tt][cc][0];
            float v = (cb[lane] + cb[lane + 64]) + (cb[lane + 128] + cb[lane + 192]);
            v = wave_reduce_sum(v);
            if (lane == 0) {
                float* dst = tt ? Cs_t : Cs_s;
                atomicAdd(&dst[b * C + c0 + sub * SUB + cc], v);
            }
        }
        __syncthreads();
    }

    const int hwb = b * HW + hw0;
#pragma unroll
    for (int j = 0; j < 4; ++j) atomicAdd(&As_s[hwb + j], as_s[j]);
#pragma unroll
    for (int j = 0; j < 4; ++j) atomicAdd(&As_t[hwb + j], as_t[j]);
}

__global__ __launch_bounds__(256) void stats_kernel(const float* __restrict__ s1, const float* __restrict__ t1,
                                                    const float* __restrict__ s2, const float* __restrict__ t2,
                                                    float* ws) {
    __shared__ float part[2][SUB][256];
    const int bid = blockIdx.x;
    if (bid < 512) {   // level 1: 8 b * 4 tiles * 16 chunks
        const int b = bid >> 6, rem = bid & 63, tile = rem >> 4, chunk = rem & 15;
        stats_level<C1, HW1>(s1, t1, ws + AS1S, ws + AS1T, ws + CS1S, ws + CS1T, b, tile, chunk, part);
    } else {           // level 2: 8 b * 1 tile * 32 chunks
        const int bid2 = bid - 512;
        const int b = bid2 >> 5, chunk = bid2 & 31;
        stats_level<C2, HW2>(s2, t2, ws + AS2S, ws + AS2T, ws + CS2S, ws + CS2T, b, 0, chunk, part);
    }
}

// ---------------- softmax + lat ----------------
__global__ __launch_bounds__(256) void softmax_kernel(float* ws) {
    __shared__ float red[4];
    const int bid = blockIdx.x;
    const int b = bid >> 2, m = bid & 3;
    const float* xa; const float* xb; float* M;
    int n; float scale, mult;
    if (m == 0)      { xa = ws + AS1S + b * HW1; xb = ws + AS1T + b * HW1; M = ws + MS1 + b * HW1; n = HW1; scale = 1.0f / C1;  mult = (float)HW1; }
    else if (m == 1) { xa = ws + CS1S + b * C1;  xb = ws + CS1T + b * C1;  M = ws + MC1 + b * C1;  n = C1;  scale = 1.0f / HW1; mult = (float)C1;  }
    else if (m == 2) { xa = ws + AS2S + b * HW2; xb = ws + AS2T + b * HW2; M = ws + MS2 + b * HW2; n = HW2; scale = 1.0f / C2;  mult = (float)HW2; }
    else             { xa = ws + CS2S + b * C2;  xb = ws + CS2T + b * C2;  M = ws + MC2 + b * C2;  n = C2;  scale = 1.0f / HW2; mult = (float)C2;  }

    const int tid = threadIdx.x;
    const float invT = 2.0f;  // 1/T, T=0.5
    float latp = 0.f, mx = -3.0e38f;
    for (int i = tid; i < n; i += 256) {
        float a = xa[i] * scale, c = xb[i] * scale;
        float d = a - c; latp += d * d;
        mx = fmaxf(mx, (a + c) * invT);
    }
    const float mxall = block_reduce_max(mx, red);
    const float latall = block_reduce_sum(latp, red);
    if (tid == 0) atomicAdd(&ws[ACC + 0], latall);

    float se = 0.f;
    for (int i = tid; i < n; i += 256) {
        float x = (xa[i] + xb[i]) * scale * invT;
        se += expf(x - mxall);
    }
    const float seall = block_reduce_sum(se, red);
    const float inv = mult / seall;
    for (int i = tid; i < n; i += 256) {
        float x = (xa[i] + xb[i]) * scale * invT;
        M[i] = expf(x - mxall) * inv;
    }
}

// ---------------- slam: sum Mc[b,c]*Ms[b,hw]*(s-t)^2 ----------------
template<int C, int HW>
__device__ void slam_level(const float* __restrict__ s, const float* __restrict__ t,
                           const float* Ms, const float* Mc, float* slam_acc,
                           int b, int tile, int chunk, float* mc, float* red) {
    const int tid = threadIdx.x;
    const int hw0 = tile * HWT + tid * 4;
    const int c0 = chunk * CCH;
    if (tid < CCH) mc[tid] = Mc[b * C + c0 + tid];
    __syncthreads();
    const size_t base = ((size_t)(b * C + c0)) * HW + hw0;
    const float4* ps = reinterpret_cast<const float4*>(s + base);
    const float4* pt = reinterpret_cast<const float4*>(t + base);
    const int cstride = HW / 4;

    float acc0 = 0.f, acc1 = 0.f, acc2 = 0.f, acc3 = 0.f;
#pragma unroll
    for (int ci = 0; ci < CCH; ++ci) {
        float4 vs = ps[(size_t)ci * cstride];
        float4 vt = pt[(size_t)ci * cstride];
        const float m = mc[ci];
        float d0 = vs.x - vt.x, d1 = vs.y - vt.y, d2 = vs.z - vt.z, d3 = vs.w - vt.w;
        acc0 = fmaf(m, d0 * d0, acc0);
        acc1 = fmaf(m, d1 * d1, acc1);
        acc2 = fmaf(m, d2 * d2, acc2);
        acc3 = fmaf(m, d3 * d3, acc3);
    }
    const float4 msv = *reinterpret_cast<const float4*>(Ms + b * HW + hw0);
    float acc = acc0 * msv.x + acc1 * msv.y + acc2 * msv.z + acc3 * msv.w;
    acc = block_reduce_sum(acc, red);
    if (tid == 0) atomicAdd(slam_acc, acc);
}

__global__ __launch_bounds__(256) void slam_kernel(const float* __restrict__ s1, const float* __restrict__ t1,
                                                   const float* __restrict__ s2, const float* __restrict__ t2,
                                                   float* ws) {
    __shared__ float mc[CCH];
    __shared__ float red[4];
    const int bid = blockIdx.x;
    if (bid < 512) {
        const int b = bid >> 6, rem = bid & 63, tile = rem >> 4, chunk = rem & 15;
        slam_level<C1, HW1>(s1, t1, ws + MS1, ws + MC1, ws + ACC + 1, b, tile, chunk, mc, red);
    } else {
        const int bid2 = bid - 512;
        const int b = bid2 >> 5, chunk = bid2 & 31;
        slam_level<C2, HW2>(s2, t2, ws + MS2, ws + MC2, ws + ACC + 2, b, 0, chunk, mc, red);
    }
}

// ---------------- epilogue ----------------
__global__ void final_kernel(const float* __restrict__ ws, float* __restrict__ out) {
    if (threadIdx.x == 0 && blockIdx.x == 0) {
        const float lat = ws[ACC + 0];
        const float lam = sqrtf(ws[ACC + 1]) + sqrtf(ws[ACC + 2]);
        // att = ATT * (A_COEF*lat + B_COEF*lam) / BS / n_levels
        const float att = (4e-4f * lat + 2e-2f * lam) / 8.0f / 2.0f;
        out[0] = att * 8.0f;
        out[1] = att;
    }
}

extern "C" void kernel_launch(void* const* d_in, const int* in_sizes, int n_in,
                              void* d_out, int out_size, void* d_ws, size_t ws_size,
                              hipStream_t stream) {
    const float* s1 = (const float*)d_in[1];
    const float* t1 = (const float*)d_in[2];
    const float* s2 = (const float*)d_in[3];
    const float* t2 = (const float*)d_in[4];
    float* ws = (float*)d_ws;
    float* out = (float*)d_out;

    // zero the atomic-accumulated region (harness does not re-poison between replays)
    hipMemsetAsync(ws, 0, (size_t)ZEND * sizeof(float), stream);

    stats_kernel<<<768, 256, 0, stream>>>(s1, t1, s2, t2, ws);
    softmax_kernel<<<32, 256, 0, stream>>>(ws);
    slam_kernel<<<768, 256, 0, stream>>>(s1, t1, s2, t2, ws);
    final_kernel<<<1, 64, 0, stream>>>(ws, out);
}

// Round 3
// 53.686 us; speedup vs baseline: 1.5407x; 1.4189x over previous
//
#include <hip/hip_runtime.h>
#include <math.h>

// Problem constants
#define B_   8
#define C1   256
#define HW1  4096   // 64*64
#define C2   512
#define HW2  1024   // 32*32

#define CCH  16     // channels per block
#define HWT  1024   // hw elements per block (256 threads * float4)
#define NCH1 16     // chunk count level 1 (C1/CCH)
#define NCH2 32     // chunk count level 2 (C2/CCH)
#define NT1  4      // hw tiles level 1 (HW1/HWT)
#define NT2  1      // hw tiles level 2

// ---------------- fast-path ws layout (floats); nothing needs pre-zeroing ----------------
#define F_LATP  0                          // 32 lat partials (one per softmax block)
#define F_SL1P  (F_LATP + 32)              // 512 slam1 partials
#define F_SL2P  (F_SL1P + 512)             // 256 slam2 partials
#define F_AP1S  (F_SL2P + 256)             // As1 partials [NCH1][B][HW1]
#define F_AP1T  (F_AP1S + NCH1*B_*HW1)
#define F_AP2S  (F_AP1T + NCH1*B_*HW1)     // As2 partials [NCH2][B][HW2]
#define F_AP2T  (F_AP2S + NCH2*B_*HW2)
#define F_CP1S  (F_AP2T + NCH2*B_*HW2)     // Cs1 partials [B][C1][NT1]
#define F_CP1T  (F_CP1S + B_*C1*NT1)
#define F_CP2S  (F_CP1T + B_*C1*NT1)       // Cs2 (complete) [B][C2]
#define F_CP2T  (F_CP2S + B_*C2)
#define F_MS1   (F_CP2T + B_*C2)
#define F_MC1   (F_MS1 + B_*HW1)
#define F_MS2   (F_MC1 + B_*C1)
#define F_MC2   (F_MS2 + B_*HW2)
#define F_END   (F_MC2 + B_*C2)
#define FAST_WS_BYTES ((size_t)F_END * 4)

// ---------------- fallback ws layout (round-2, atomic-based) ----------------
#define ACC   0
#define AS1S  4
#define AS1T  (AS1S + B_*HW1)
#define CS1S  (AS1T + B_*HW1)
#define CS1T  (CS1S + B_*C1)
#define AS2S  (CS1T + B_*C1)
#define AS2T  (AS2S + B_*HW2)
#define CS2S  (AS2T + B_*HW2)
#define CS2T  (CS2S + B_*C2)
#define ZEND  (CS2T + B_*C2)
#define MS1   ZEND
#define MC1   (MS1 + B_*HW1)
#define MS2   (MC1 + B_*C1)
#define MC2   (MS2 + B_*HW2)

__device__ __forceinline__ float wave_reduce_sum(float v) {
#pragma unroll
    for (int off = 1; off < 64; off <<= 1) v += __shfl_xor(v, off, 64);
    return v;
}
__device__ __forceinline__ float wave_reduce_max(float v) {
#pragma unroll
    for (int off = 1; off < 64; off <<= 1) v = fmaxf(v, __shfl_xor(v, off, 64));
    return v;
}
__device__ __forceinline__ float block_reduce_sum(float v, float* red) {
    const int lane = threadIdx.x & 63, wid = threadIdx.x >> 6;
    v = wave_reduce_sum(v);
    if (lane == 0) red[wid] = v;
    __syncthreads();
    v = red[0] + red[1] + red[2] + red[3];
    __syncthreads();
    return v;
}
__device__ __forceinline__ float block_reduce_max(float v, float* red) {
    const int lane = threadIdx.x & 63, wid = threadIdx.x >> 6;
    v = wave_reduce_max(v);
    if (lane == 0) red[wid] = v;
    __syncthreads();
    v = fmaxf(fmaxf(red[0], red[1]), fmaxf(red[2], red[3]));
    __syncthreads();
    return v;
}

// ============================== FAST PATH ==============================

// stats: hot loop = 32 independent float4 loads + abs/add. No LDS, no barrier,
// no atomics until the single end-phase. As partials: plain float4 stores.
// Cs partials: one LDS transpose + shuffle reduce + plain stores.
template<int C, int HW, int NT>
__device__ void stats_fast_level(const float* __restrict__ s, const float* __restrict__ t,
                                 float* __restrict__ APs, float* __restrict__ APt,
                                 float* __restrict__ CPs, float* __restrict__ CPt,
                                 int b, int tile, int chunk, float (*part)[256]) {
    const int tid = threadIdx.x, lane = tid & 63, wid = tid >> 6;
    const int hw0 = tile * HWT + tid * 4;
    const int c0 = chunk * CCH;
    const size_t base = ((size_t)(b * C + c0)) * HW + hw0;
    const float4* ps = reinterpret_cast<const float4*>(s + base);
    const float4* pt = reinterpret_cast<const float4*>(t + base);
    const int cstride = HW / 4;

    float as0 = 0.f, as1 = 0.f, as2 = 0.f, as3 = 0.f;
    float at0 = 0.f, at1 = 0.f, at2 = 0.f, at3 = 0.f;
    float css[CCH], cst[CCH];

#pragma unroll
    for (int ci = 0; ci < CCH; ++ci) {
        float4 vs = ps[(size_t)ci * cstride];
        float4 vt = pt[(size_t)ci * cstride];
        float a0 = fabsf(vs.x), a1 = fabsf(vs.y), a2 = fabsf(vs.z), a3 = fabsf(vs.w);
        float b0 = fabsf(vt.x), b1 = fabsf(vt.y), b2 = fabsf(vt.z), b3 = fabsf(vt.w);
        as0 += a0; as1 += a1; as2 += a2; as3 += a3;
        at0 += b0; at1 += b1; at2 += b2; at3 += b3;
        css[ci] = (a0 + a1) + (a2 + a3);
        cst[ci] = (b0 + b1) + (b2 + b3);
    }

    // spatial partials: plain vector stores (no atomics)
    const size_t ap = ((size_t)chunk * B_ + b) * HW + hw0;
    *reinterpret_cast<float4*>(APs + ap) = make_float4(as0, as1, as2, as3);
    *reinterpret_cast<float4*>(APt + ap) = make_float4(at0, at1, at2, at3);

    // channel partials: transpose via LDS, one reduce phase
#pragma unroll
    for (int ci = 0; ci < CCH; ++ci) {
        part[ci][tid] = css[ci];
        part[CCH + ci][tid] = cst[ci];
    }
    __syncthreads();
#pragma unroll
    for (int k = 0; k < 8; ++k) {            // 4 waves * 8 rows = 32 rows
        const int r = wid * 8 + k;
        const float* cb = part[r];
        float v = (cb[lane] + cb[lane + 64]) + (cb[lane + 128] + cb[lane + 192]);
        v = wave_reduce_sum(v);
        if (lane == 0) {
            const int cc = r & (CCH - 1);
            float* dst = (r < CCH) ? CPs : CPt;
            dst[((size_t)b * C + c0 + cc) * NT + tile] = v;
        }
    }
}

__global__ __launch_bounds__(256) void stats_fast(const float* __restrict__ s1, const float* __restrict__ t1,
                                                  const float* __restrict__ s2, const float* __restrict__ t2,
                                                  float* ws) {
    __shared__ float part[2 * CCH][256];   // 32 KB
    const int bid = blockIdx.x;
    if (bid < 512) {   // level 1: 8 b * 4 tiles * 16 chunks
        const int b = bid >> 6, rem = bid & 63, tile = rem >> 4, chunk = rem & 15;
        stats_fast_level<C1, HW1, NT1>(s1, t1, ws + F_AP1S, ws + F_AP1T, ws + F_CP1S, ws + F_CP1T,
                                       b, tile, chunk, part);
    } else {           // level 2: 8 b * 32 chunks (one hw tile)
        const int bid2 = bid - 512;
        const int b = bid2 >> 5, chunk = bid2 & 31;
        stats_fast_level<C2, HW2, NT2>(s2, t2, ws + F_AP2S, ws + F_AP2T, ws + F_CP2S, ws + F_CP2T,
                                       b, 0, chunk, part);
    }
}

// softmax: gather partials -> LDS, lat partial + masks. 32 blocks.
__global__ __launch_bounds__(256) void softmax_fast(float* ws) {
    __shared__ float sa[HW1], sb[HW1];     // 32 KB
    __shared__ float red[4];
    const int bid = blockIdx.x;
    const int b = bid >> 2, m = bid & 3;
    const int tid = threadIdx.x;

    int n; float scale, mult; float* M;
    if (m == 0)      { n = HW1; scale = 1.0f / C1;  mult = (float)HW1; M = ws + F_MS1 + b * HW1; }
    else if (m == 1) { n = C1;  scale = 1.0f / HW1; mult = (float)C1;  M = ws + F_MC1 + b * C1;  }
    else if (m == 2) { n = HW2; scale = 1.0f / C2;  mult = (float)HW2; M = ws + F_MS2 + b * HW2; }
    else             { n = C2;  scale = 1.0f / HW2; mult = (float)C2;  M = ws + F_MC2 + b * C2;  }

    // gather partials into LDS (each thread owns i = tid, tid+256, ...)
    if (m == 0) {
        const float* As = ws + F_AP1S + b * HW1;
        const float* At = ws + F_AP1T + b * HW1;
        for (int i = tid; i < HW1; i += 256) {
            float a = 0.f, c = 0.f;
#pragma unroll
            for (int k = 0; k < NCH1; ++k) {
                a += As[(size_t)k * B_ * HW1 + i];
                c += At[(size_t)k * B_ * HW1 + i];
            }
            sa[i] = a * scale; sb[i] = c * scale;
        }
    } else if (m == 1) {
        if (tid < C1) {
            float4 v = *reinterpret_cast<const float4*>(ws + F_CP1S + ((size_t)b * C1 + tid) * 4);
            float4 w = *reinterpret_cast<const float4*>(ws + F_CP1T + ((size_t)b * C1 + tid) * 4);
            sa[tid] = ((v.x + v.y) + (v.z + v.w)) * scale;
            sb[tid] = ((w.x + w.y) + (w.z + w.w)) * scale;
        }
    } else if (m == 2) {
        const float* As = ws + F_AP2S + b * HW2;
        const float* At = ws + F_AP2T + b * HW2;
        for (int i = tid; i < HW2; i += 256) {
            float a = 0.f, c = 0.f;
#pragma unroll
            for (int k = 0; k < NCH2; ++k) {
                a += As[(size_t)k * B_ * HW2 + i];
                c += At[(size_t)k * B_ * HW2 + i];
            }
            sa[i] = a * scale; sb[i] = c * scale;
        }
    } else {
        for (int i = tid; i < C2; i += 256) {
            sa[i] = ws[F_CP2S + b * C2 + i] * scale;
            sb[i] = ws[F_CP2T + b * C2 + i] * scale;
        }
    }

    const float invT = 2.0f;  // 1/T, T=0.5
    float latp = 0.f, mx = -3.0e38f;
    for (int i = tid; i < n; i += 256) {
        float d = sa[i] - sb[i];
        latp += d * d;
        mx = fmaxf(mx, (sa[i] + sb[i]) * invT);
    }
    const float mxall = block_reduce_max(mx, red);
    const float latall = block_reduce_sum(latp, red);
    if (tid == 0) ws[F_LATP + bid] = latall;

    float se = 0.f;
    for (int i = tid; i < n; i += 256) {
        se += expf((sa[i] + sb[i]) * invT - mxall);
    }
    const float seall = block_reduce_sum(se, red);
    const float inv = mult / seall;
    for (int i = tid; i < n; i += 256) {
        M[i] = expf((sa[i] + sb[i]) * invT - mxall) * inv;
    }
}

// slam: clean float4 hot loop, block reduce, per-block partial slot (no atomics)
template<int C, int HW>
__device__ void slam_fast_level(const float* __restrict__ s, const float* __restrict__ t,
                                const float* Ms, const float* Mc, float* slot,
                                int b, int tile, int chunk, float* mc, float* red) {
    const int tid = threadIdx.x;
    const int hw0 = tile * HWT + tid * 4;
    const int c0 = chunk * CCH;
    if (tid < CCH) mc[tid] = Mc[b * C + c0 + tid];
    __syncthreads();
    const size_t base = ((size_t)(b * C + c0)) * HW + hw0;
    const float4* ps = reinterpret_cast<const float4*>(s + base);
    const float4* pt = reinterpret_cast<const float4*>(t + base);
    const int cstride = HW / 4;

    float acc0 = 0.f, acc1 = 0.f, acc2 = 0.f, acc3 = 0.f;
#pragma unroll
    for (int ci = 0; ci < CCH; ++ci) {
        float4 vs = ps[(size_t)ci * cstride];
        float4 vt = pt[(size_t)ci * cstride];
        const float m = mc[ci];
        float d0 = vs.x - vt.x, d1 = vs.y - vt.y, d2 = vs.z - vt.z, d3 = vs.w - vt.w;
        acc0 = fmaf(m, d0 * d0, acc0);
        acc1 = fmaf(m, d1 * d1, acc1);
        acc2 = fmaf(m, d2 * d2, acc2);
        acc3 = fmaf(m, d3 * d3, acc3);
    }
    const float4 msv = *reinterpret_cast<const float4*>(Ms + b * HW + hw0);
    float acc = acc0 * msv.x + acc1 * msv.y + acc2 * msv.z + acc3 * msv.w;
    acc = block_reduce_sum(acc, red);
    if (tid == 0) *slot = acc;
}

__global__ __launch_bounds__(256) void slam_fast(const float* __restrict__ s1, const float* __restrict__ t1,
                                                 const float* __restrict__ s2, const float* __restrict__ t2,
                                                 float* ws) {
    __shared__ float mc[CCH];
    __shared__ float red[4];
    const int bid = blockIdx.x;
    if (bid < 512) {
        const int b = bid >> 6, rem = bid & 63, tile = rem >> 4, chunk = rem & 15;
        slam_fast_level<C1, HW1>(s1, t1, ws + F_MS1, ws + F_MC1, ws + F_SL1P + bid, b, tile, chunk, mc, red);
    } else {
        const int bid2 = bid - 512;
        const int b = bid2 >> 5, chunk = bid2 & 31;
        slam_fast_level<C2, HW2>(s2, t2, ws + F_MS2, ws + F_MC2, ws + F_SL2P + bid2, b, 0, chunk, mc, red);
    }
}

__global__ __launch_bounds__(256) void final_fast(const float* __restrict__ ws, float* __restrict__ out) {
    __shared__ float red[4];
    const int tid = threadIdx.x;
    float lat = 0.f, p1 = 0.f, p2 = 0.f;
    for (int i = tid; i < 32; i += 256)  lat += ws[F_LATP + i];
    for (int i = tid; i < 512; i += 256) p1 += ws[F_SL1P + i];
    for (int i = tid; i < 256; i += 256) p2 += ws[F_SL2P + i];
    lat = block_reduce_sum(lat, red);
    p1 = block_reduce_sum(p1, red);
    p2 = block_reduce_sum(p2, red);
    if (tid == 0) {
        const float lam = sqrtf(p1) + sqrtf(p2);
        const float att = (4e-4f * lat + 2e-2f * lam) / 8.0f / 2.0f;
        out[0] = att * 8.0f;
        out[1] = att;
    }
}

// ============================== FALLBACK (round-2, proven) ==============================

template<int C, int HW>
__device__ void stats_level_fb(const float* __restrict__ s, const float* __restrict__ t,
                               float* As_s, float* As_t, float* Cs_s, float* Cs_t,
                               int b, int tile, int chunk, float (*part)[8][256]) {
    const int tid = threadIdx.x, lane = tid & 63, wid = tid >> 6;
    const int hw0 = tile * HWT + tid * 4;
    const int c0 = chunk * CCH;
    const size_t base = ((size_t)(b * C + c0)) * HW + hw0;
    const float4* ps = reinterpret_cast<const float4*>(s + base);
    const float4* pt = reinterpret_cast<const float4*>(t + base);
    const int cstride = HW / 4;

    float as_s[4] = {0.f, 0.f, 0.f, 0.f};
    float as_t[4] = {0.f, 0.f, 0.f, 0.f};

#pragma unroll
    for (int sub = 0; sub < 2; ++sub) {
#pragma unroll
        for (int ci = 0; ci < 8; ++ci) {
            const int cc = sub * 8 + ci;
            float4 vs = ps[(size_t)cc * cstride];
            float4 vt = pt[(size_t)cc * cstride];
            float a0 = fabsf(vs.x), a1 = fabsf(vs.y), a2 = fabsf(vs.z), a3 = fabsf(vs.w);
            float b0 = fabsf(vt.x), b1 = fabsf(vt.y), b2 = fabsf(vt.z), b3 = fabsf(vt.w);
            as_s[0] += a0; as_s[1] += a1; as_s[2] += a2; as_s[3] += a3;
            as_t[0] += b0; as_t[1] += b1; as_t[2] += b2; as_t[3] += b3;
            part[0][ci][tid] = (a0 + a1) + (a2 + a3);
            part[1][ci][tid] = (b0 + b1) + (b2 + b3);
        }
        __syncthreads();
#pragma unroll
        for (int k = 0; k < 4; ++k) {
            const int col = (wid << 2) | k;
            const int tt = col >> 3, cc = col & 7;
            const float* cb = &part[tt][cc][0];
            float v = (cb[lane] + cb[lane + 64]) + (cb[lane + 128] + cb[lane + 192]);
            v = wave_reduce_sum(v);
            if (lane == 0) {
                float* dst = tt ? Cs_t : Cs_s;
                atomicAdd(&dst[b * C + c0 + sub * 8 + cc], v);
            }
        }
        __syncthreads();
    }
    const int hwb = b * HW + hw0;
#pragma unroll
    for (int j = 0; j < 4; ++j) atomicAdd(&As_s[hwb + j], as_s[j]);
#pragma unroll
    for (int j = 0; j < 4; ++j) atomicAdd(&As_t[hwb + j], as_t[j]);
}

__global__ __launch_bounds__(256) void stats_fb(const float* __restrict__ s1, const float* __restrict__ t1,
                                                const float* __restrict__ s2, const float* __restrict__ t2,
                                                float* ws) {
    __shared__ float part[2][8][256];
    const int bid = blockIdx.x;
    if (bid < 512) {
        const int b = bid >> 6, rem = bid & 63, tile = rem >> 4, chunk = rem & 15;
        stats_level_fb<C1, HW1>(s1, t1, ws + AS1S, ws + AS1T, ws + CS1S, ws + CS1T, b, tile, chunk, part);
    } else {
        const int bid2 = bid - 512;
        const int b = bid2 >> 5, chunk = bid2 & 31;
        stats_level_fb<C2, HW2>(s2, t2, ws + AS2S, ws + AS2T, ws + CS2S, ws + CS2T, b, 0, chunk, part);
    }
}

__global__ __launch_bounds__(256) void softmax_fb(float* ws) {
    __shared__ float red[4];
    const int bid = blockIdx.x;
    const int b = bid >> 2, m = bid & 3;
    const float* xa; const float* xb; float* M;
    int n; float scale, mult;
    if (m == 0)      { xa = ws + AS1S + b * HW1; xb = ws + AS1T + b * HW1; M = ws + MS1 + b * HW1; n = HW1; scale = 1.0f / C1;  mult = (float)HW1; }
    else if (m == 1) { xa = ws + CS1S + b * C1;  xb = ws + CS1T + b * C1;  M = ws + MC1 + b * C1;  n = C1;  scale = 1.0f / HW1; mult = (float)C1;  }
    else if (m == 2) { xa = ws + AS2S + b * HW2; xb = ws + AS2T + b * HW2; M = ws + MS2 + b * HW2; n = HW2; scale = 1.0f / C2;  mult = (float)HW2; }
    else             { xa = ws + CS2S + b * C2;  xb = ws + CS2T + b * C2;  M = ws + MC2 + b * C2;  n = C2;  scale = 1.0f / HW2; mult = (float)C2;  }

    const int tid = threadIdx.x;
    const float invT = 2.0f;
    float latp = 0.f, mx = -3.0e38f;
    for (int i = tid; i < n; i += 256) {
        float a = xa[i] * scale, c = xb[i] * scale;
        float d = a - c; latp += d * d;
        mx = fmaxf(mx, (a + c) * invT);
    }
    const float mxall = block_reduce_max(mx, red);
    const float latall = block_reduce_sum(latp, red);
    if (tid == 0) atomicAdd(&ws[ACC + 0], latall);

    float se = 0.f;
    for (int i = tid; i < n; i += 256) {
        float x = (xa[i] + xb[i]) * scale * invT;
        se += expf(x - mxall);
    }
    const float seall = block_reduce_sum(se, red);
    const float inv = mult / seall;
    for (int i = tid; i < n; i += 256) {
        float x = (xa[i] + xb[i]) * scale * invT;
        M[i] = expf(x - mxall) * inv;
    }
}

template<int C, int HW>
__device__ void slam_level_fb(const float* __restrict__ s, const float* __restrict__ t,
                              const float* Ms, const float* Mc, float* slam_acc,
                              int b, int tile, int chunk, float* mc, float* red) {
    const int tid = threadIdx.x;
    const int hw0 = tile * HWT + tid * 4;
    const int c0 = chunk * CCH;
    if (tid < CCH) mc[tid] = Mc[b * C + c0 + tid];
    __syncthreads();
    const size_t base = ((size_t)(b * C + c0)) * HW + hw0;
    const float4* ps = reinterpret_cast<const float4*>(s + base);
    const float4* pt = reinterpret_cast<const float4*>(t + base);
    const int cstride = HW / 4;
    float acc0 = 0.f, acc1 = 0.f, acc2 = 0.f, acc3 = 0.f;
#pragma unroll
    for (int ci = 0; ci < CCH; ++ci) {
        float4 vs = ps[(size_t)ci * cstride];
        float4 vt = pt[(size_t)ci * cstride];
        const float m = mc[ci];
        float d0 = vs.x - vt.x, d1 = vs.y - vt.y, d2 = vs.z - vt.z, d3 = vs.w - vt.w;
        acc0 = fmaf(m, d0 * d0, acc0);
        acc1 = fmaf(m, d1 * d1, acc1);
        acc2 = fmaf(m, d2 * d2, acc2);
        acc3 = fmaf(m, d3 * d3, acc3);
    }
    const float4 msv = *reinterpret_cast<const float4*>(Ms + b * HW + hw0);
    float acc = acc0 * msv.x + acc1 * msv.y + acc2 * msv.z + acc3 * msv.w;
    acc = block_reduce_sum(acc, red);
    if (tid == 0) atomicAdd(slam_acc, acc);
}

__global__ __launch_bounds__(256) void slam_fb(const float* __restrict__ s1, const float* __restrict__ t1,
                                               const float* __restrict__ s2, const float* __restrict__ t2,
                                               float* ws) {
    __shared__ float mc[CCH];
    __shared__ float red[4];
    const int bid = blockIdx.x;
    if (bid < 512) {
        const int b = bid >> 6, rem = bid & 63, tile = rem >> 4, chunk = rem & 15;
        slam_level_fb<C1, HW1>(s1, t1, ws + MS1, ws + MC1, ws + ACC + 1, b, tile, chunk, mc, red);
    } else {
        const int bid2 = bid - 512;
        const int b = bid2 >> 5, chunk = bid2 & 31;
        slam_level_fb<C2, HW2>(s2, t2, ws + MS2, ws + MC2, ws + ACC + 2, b, 0, chunk, mc, red);
    }
}

__global__ void final_fb(const float* __restrict__ ws, float* __restrict__ out) {
    if (threadIdx.x == 0 && blockIdx.x == 0) {
        const float lat = ws[ACC + 0];
        const float lam = sqrtf(ws[ACC + 1]) + sqrtf(ws[ACC + 2]);
        const float att = (4e-4f * lat + 2e-2f * lam) / 8.0f / 2.0f;
        out[0] = att * 8.0f;
        out[1] = att;
    }
}

// ============================== launch ==============================

extern "C" void kernel_launch(void* const* d_in, const int* in_sizes, int n_in,
                              void* d_out, int out_size, void* d_ws, size_t ws_size,
                              hipStream_t stream) {
    (void)in_sizes; (void)n_in; (void)out_size;
    const float* s1 = (const float*)d_in[1];
    const float* t1 = (const float*)d_in[2];
    const float* s2 = (const float*)d_in[3];
    const float* t2 = (const float*)d_in[4];
    float* ws = (float*)d_ws;
    float* out = (float*)d_out;

    if (ws_size >= FAST_WS_BYTES) {
        // no memset needed: every ws slot is written before it is read
        stats_fast<<<768, 256, 0, stream>>>(s1, t1, s2, t2, ws);
        softmax_fast<<<32, 256, 0, stream>>>(ws);
        slam_fast<<<768, 256, 0, stream>>>(s1, t1, s2, t2, ws);
        final_fast<<<1, 256, 0, stream>>>(ws, out);
    } else {
        hipMemsetAsync(ws, 0, (size_t)ZEND * sizeof(float), stream);
        stats_fb<<<768, 256, 0, stream>>>(s1, t1, s2, t2, ws);
        softmax_fb<<<32, 256, 0, stream>>>(ws);
        slam_fb<<<768, 256, 0, stream>>>(s1, t1, s2, t2, ws);
        final_fb<<<1, 64, 0, stream>>>(ws, out);
    }
}